// Round 14
// baseline (287.554 us; speedup 1.0000x reference)
//
#include <hip/hip_runtime.h>
#include <stdint.h>

#define HW    50176   // 224*224
#define BATCH 16
#define NSEG  196
#define EMB   16
#define MC    16
#define JITTER 0.001f
#define EBLK  14      // emb blocks per batch
#define PXB   3584    // pixels per emb block (50176/14)

// ---------------- threefry2x32 (20 rounds), bit-exact vs JAX ----------------
__host__ __device__ inline void threefry2x32(uint32_t k0, uint32_t k1,
                                             uint32_t x0, uint32_t x1,
                                             uint32_t& o0, uint32_t& o1) {
  uint32_t k2 = k0 ^ k1 ^ 0x1BD11BDAu;
#define TFR(r) { x0 += x1; x1 = (x1 << (r)) | (x1 >> (32 - (r))); x1 ^= x0; }
  x0 += k0; x1 += k1;
  TFR(13) TFR(15) TFR(26) TFR(6)
  x0 += k1; x1 += k2 + 1u;
  TFR(17) TFR(29) TFR(16) TFR(24)
  x0 += k2; x1 += k0 + 2u;
  TFR(13) TFR(15) TFR(26) TFR(6)
  x0 += k0; x1 += k1 + 3u;
  TFR(17) TFR(29) TFR(16) TFR(24)
  x0 += k1; x1 += k2 + 4u;
  TFR(13) TFR(15) TFR(26) TFR(6)
  x0 += k2; x1 += k0 + 5u;
#undef TFR
  o0 = x0; o1 = x1;
}

// XLA ErfInv (f32), Giles polynomial
__device__ inline float erfinv_f32(float x) {
  float w = -log1pf(-x * x);
  float p;
  if (w < 5.0f) {
    w = w - 2.5f;
    p = 2.81022636e-08f;
    p = 3.43273939e-07f + p * w;
    p = -3.5233877e-06f + p * w;
    p = -4.39150654e-06f + p * w;
    p = 0.00021858087f + p * w;
    p = -0.00125372503f + p * w;
    p = -0.00417768164f + p * w;
    p = 0.246640727f + p * w;
    p = 1.50140941f + p * w;
  } else {
    w = sqrtf(w) - 3.0f;
    p = -0.000200214257f;
    p = 0.000100950558f + p * w;
    p = 0.00134934322f + p * w;
    p = -0.00367342844f + p * w;
    p = 0.00573950773f + p * w;
    p = -0.0076224613f + p * w;
    p = 0.00943887047f + p * w;
    p = 1.00167406f + p * w;
    p = 2.83297682f + p * w;
  }
  return p * x;
}

__device__ inline float bits_to_f01(uint32_t bits) {
  uint32_t fb = (bits >> 9) | 0x3F800000u;
  return __uint_as_float(fb) - 1.0f;
}

// wave-uniform broadcast via v_readlane (bit-identical to __shfl for uniform
// lane index with all lanes active; lands in SGPR)
__device__ inline float readlane_f(float v, int lane) {
  return __int_as_float(__builtin_amdgcn_readlane(__float_as_int(v), lane));
}

// ---------------- K1: pixel_probs + per-block segment sums of x,cnt --------
// Linearity: sum_emb_j[g] = W[j,:].sum_x[g] + b_j*cnt[g]; accumulate only
// 3 input channels + count.  partial: [b*EBLK+bb][4][196] (c-major).
__global__ __launch_bounds__(256) void emb_kernel(
    const float* __restrict__ x, const int* __restrict__ groups,
    const float* __restrict__ Wc, const float* __restrict__ bc,
    float* __restrict__ partial, float* __restrict__ pixel_probs) {
  __shared__ float lsum[4 * NSEG];  // [c][g]
  int b = blockIdx.x / EBLK;
  int blk = blockIdx.x % EBLK;
  int tid = threadIdx.x;
  for (int i = tid; i < 4 * NSEG; i += 256) lsum[i] = 0.0f;
  __syncthreads();
  const float* xb = x + (size_t)b * 3 * HW;
  float w0 = Wc[0], w1 = Wc[1], w2 = Wc[2], b0 = bc[0];
  for (int k = 0; k < PXB / 256; ++k) {
    int p = blk * PXB + k * 256 + tid;
    float x0 = xb[p], x1 = xb[HW + p], x2 = xb[2 * HW + p];
    int g = groups[b * HW + p];
    float e = w0 * x0 + w1 * x1;
    e = e + w2 * x2 + b0;
    pixel_probs[b * HW + p] = 1.0f / (1.0f + expf(-e));
    atomicAdd(&lsum[g], x0);
    atomicAdd(&lsum[NSEG + g], x1);
    atomicAdd(&lsum[2 * NSEG + g], x2);
    atomicAdd(&lsum[3 * NSEG + g], 1.0f);
  }
  __syncthreads();
  float* pb = partial + (size_t)blockIdx.x * (4 * NSEG);
  if (tid < NSEG) {
#pragma unroll
    for (int c = 0; c < 4; ++c) pb[c * NSEG + tid] = lsum[c * NSEG + tid];
  }
}

// ---------------- K2: FUSED stats + sigma + rng + PANEL Cholesky + hard ----
// One block per batch.  PANEL-BLOCKED factorization this round: R12/R13's
// per-step __syncthreads (196 barriers x ~1000 cyc = the measured 1175
// cyc/step clock) is replaced by 4 panel phases.  Wave P factors panel P
// (rows 64P..64P+63) serially with intra-wave readlane broadcast (no
// barriers), publishing each pivot's {gk[15], invd, beta} to a
// double-buffered LDS panel buffer; ONE barrier per panel; waves > P then
// apply the panel's 64 rank-1 updates to their rows (issue-bound, LDS gk
// reads prefetchable).  Buffer parity: panel P uses pbuf[P&1]; panel P-1's
// readers provably drain before panel P+1's factor begins (uniform barrier
// count), so no read/write overlap.
// BIT-IDENTITY: each row sees k=0..195 ascending with the exact per-k op
// sequence of R11-R13 (dot j-asc -> w -> acc m-asc -> bd -> update j-asc);
// gk bits pass through LDS unchanged; invd/beta come from the same
// tree-norm/rsq/rcp chain.  Output bit-identical to rounds 11/12/13.
__global__ __launch_bounds__(256, 1) void fused_kernel(
    const float* __restrict__ partial, const float* __restrict__ Wc,
    const float* __restrict__ bc,
    uint32_t kg0, uint32_t kg1, uint32_t ku0, uint32_t ku1,
    float* __restrict__ group_probs, float* __restrict__ sigma_out,
    float* __restrict__ hard) {
  int b = blockIdx.x;
  int tid = threadIdx.x;
  int lane = tid & 63;
  int wave = tid >> 6;
  __shared__ float ge[15][NSEG];                      // 11.76 KB
  __shared__ float mu_l[NSEG];
  __shared__ float eps_lds[NSEG * MC];                // 12.25 KB
  __shared__ __align__(16) float pbuf[2][64][20];     // 10.24 KB: gk[15],invd,beta

  // eps = sqrt(2)*erfinv(bits) straight into LDS
  for (int t = tid; t < NSEG * MC; t += 256) {
    uint32_t a0, a1;
    threefry2x32(kg0, kg1, 0u, (uint32_t)(b * NSEG * MC + t), a0, a1);
    float f = bits_to_f01(a0 ^ a1);
    const float lo = -0.99999994f;  // nextafter(-1,0)
    float u = fmaxf(lo, f * (1.0f - lo) + lo);
    eps_lds[t] = 1.4142135623730951f * erfinv_f32(u);
  }

  // stats (identical op order to R12/R13)
  if (tid < NSEG) {
    float sx0 = 0.0f, sx1 = 0.0f, sx2 = 0.0f, cn = 0.0f;
    for (int bb = 0; bb < EBLK; ++bb) {
      const float* pb = partial + (size_t)(b * EBLK + bb) * (4 * NSEG);
      sx0 += pb[tid]; sx1 += pb[NSEG + tid];
      sx2 += pb[2 * NSEG + tid]; cn += pb[3 * NSEG + tid];
    }
    float denom = fmaxf(cn, 1.0f);
#pragma unroll
    for (int j = 0; j < EMB; ++j) {
      float e = Wc[j * 3 + 0] * sx0 + Wc[j * 3 + 1] * sx1;
      e = e + Wc[j * 3 + 2] * sx2 + bc[j] * cn;
      float v = e / denom;
      if (j == 0) {
        mu_l[tid] = v;
        group_probs[b * NSEG + tid] = 1.0f / (1.0f + expf(-v));
      } else {
        ge[j - 1][tid] = v;
      }
    }
  }
  __syncthreads();  // ge, mu_l, eps_lds visible

  // sigma = G G^T + jitter*I (same fma order as R12/R13)
  if (tid < NSEG) {
    int t = tid;
    float gt[15];
#pragma unroll
    for (int j = 0; j < 15; ++j) gt[j] = ge[j][t];
    for (int s = 0; s < NSEG; ++s) {
      float a = 0.0f;
#pragma unroll
      for (int j = 0; j < 15; ++j) a = fmaf(ge[j][s], gt[j], a);  // broadcast
      if (s == t) a += JITTER;
      sigma_out[((size_t)b * NSEG + s) * NSEG + t] = a;
    }
  }

  // panel-blocked row-split Cholesky + L@eps
  int i = tid;  // this thread's row
  float g[15];
#pragma unroll
  for (int j = 0; j < 15; ++j) g[j] = (i < NSEG) ? ge[j][i] : 0.0f;
  float acc[16];
#pragma unroll
  for (int m = 0; m < 16; ++m) acc[m] = 0.0f;
  __syncthreads();  // everyone has loaded ge rows (pbuf not yet touched)

  const float sj = 0.031622776601683794f;  // sqrt(jitter)

// R11 tree norm + rsq/rcp scalar chain (verbatim; bit-identical)
#define SCALAR_CHAIN()                                                      \
    float t0 = fmaf(gk[0], gk[0], JITTER);                                  \
    float t1 = gk[1] * gk[1];   float t2 = gk[2] * gk[2];                   \
    float t3 = gk[3] * gk[3];   float t4 = gk[4] * gk[4];                   \
    float t5 = gk[5] * gk[5];   float t6 = gk[6] * gk[6];                   \
    float t7 = gk[7] * gk[7];   float t8 = gk[8] * gk[8];                   \
    float t9 = gk[9] * gk[9];   float t10 = gk[10] * gk[10];                \
    float t11 = gk[11] * gk[11]; float t12 = gk[12] * gk[12];               \
    float t13 = gk[13] * gk[13]; float t14 = gk[14] * gk[14];               \
    float u0 = t0 + t1, u1 = t2 + t3, u2 = t4 + t5, u3 = t6 + t7;           \
    float u4 = t8 + t9, u5 = t10 + t11, u6 = t12 + t13;                     \
    float v0 = u0 + u1, v1 = u2 + u3, v2 = u4 + u5, v3 = u6 + t14;          \
    float jn = (v0 + v1) + (v2 + v3);                                       \
    float invd = __builtin_amdgcn_rsqf(jn);                                 \
    float dd = jn * invd;                                                   \
    float beta = (invd * invd) * __builtin_amdgcn_rcpf(fmaf(sj, invd, 1.0f));

  for (int P = 0; P < 4; ++P) {
    const int kbase = P * 64;
    const int plen = (P == 3) ? (NSEG - 192) : 64;  // 64,64,64,4
    if (wave == P) {
      // ---- factor panel P: serial, intra-wave, no barriers ----
      for (int kk = 0; kk < plen; ++kk) {
        int owner = kk;
        float gk[15];
#pragma unroll
        for (int j = 0; j < 15; ++j) gk[j] = readlane_f(g[j], owner);
        SCALAR_CHAIN()
        if (lane == 0) {  // publish wave-uniform pivot data
          float* pw = &pbuf[P & 1][kk][0];
#pragma unroll
          for (int j = 0; j < 15; ++j) pw[j] = gk[j];
          pw[15] = invd;
          pw[16] = beta;
        }
        const float4* ep = (const float4*)(eps_lds + (kbase + kk) * MC);
        float4 e0 = ep[0], e1 = ep[1], e2 = ep[2], e3 = ep[3];
        float ek[16] = {e0.x, e0.y, e0.z, e0.w, e1.x, e1.y, e1.z, e1.w,
                        e2.x, e2.y, e2.z, e2.w, e3.x, e3.y, e3.z, e3.w};
        float dot = 0.0f;
#pragma unroll
        for (int j = 0; j < 15; ++j) dot = fmaf(g[j], gk[j], dot);
        float w = (lane > owner) ? dot * invd : ((lane == owner) ? dd : 0.0f);
#pragma unroll
        for (int m = 0; m < 16; ++m) acc[m] = fmaf(w, ek[m], acc[m]);
        float bd = beta * dot;
#pragma unroll
        for (int j = 0; j < 15; ++j) g[j] = fmaf(-bd, gk[j], g[j]);
      }
    }
    __syncthreads();  // panel P fully published; ONE barrier per panel
    if (wave > P) {
      // ---- apply panel P's rank-1 updates to this wave's rows ----
      for (int kk = 0; kk < plen; ++kk) {
        const float* pv = &pbuf[P & 1][kk][0];
        float4 p0 = *(const float4*)(pv);
        float4 p1 = *(const float4*)(pv + 4);
        float4 p2 = *(const float4*)(pv + 8);
        float4 p3 = *(const float4*)(pv + 12);  // {g12,g13,g14,invd}
        float gk[15] = {p0.x, p0.y, p0.z, p0.w, p1.x, p1.y, p1.z, p1.w,
                        p2.x, p2.y, p2.z, p2.w, p3.x, p3.y, p3.z};
        float invd = p3.w;
        float beta = pv[16];
        const float4* ep = (const float4*)(eps_lds + (kbase + kk) * MC);
        float4 e0 = ep[0], e1 = ep[1], e2 = ep[2], e3 = ep[3];
        float ek[16] = {e0.x, e0.y, e0.z, e0.w, e1.x, e1.y, e1.z, e1.w,
                        e2.x, e2.y, e2.z, e2.w, e3.x, e3.y, e3.z, e3.w};
        float dot = 0.0f;
#pragma unroll
        for (int j = 0; j < 15; ++j) dot = fmaf(g[j], gk[j], dot);
        float w = dot * invd;  // i > k always here; dead rows g==+0 -> w=+0
#pragma unroll
        for (int m = 0; m < 16; ++m) acc[m] = fmaf(w, ek[m], acc[m]);
        float bd = beta * dot;
#pragma unroll
        for (int j = 0; j < 15; ++j) g[j] = fmaf(-bd, gk[j], g[j]);
      }
    }
  }
#undef SCALAR_CHAIN

  // epilogue: hard = (mu + L@eps + logistic) > 0
  if (i < NSEG) {
    float mui = mu_l[i];
    float4 outv[4];
    float* op = (float*)outv;
#pragma unroll
    for (int m = 0; m < 16; ++m) {
      uint32_t a0, a1;
      threefry2x32(ku0, ku1, 0u, (uint32_t)(b * NSEG * MC + i * MC + m), a0, a1);
      float f = bits_to_f01(a0 ^ a1);
      const float mn = 1e-6f;
      const float mx = (float)(1.0 - 1e-6);
      float uu = fmaxf(mn, f * (mx - mn) + mn);
      float lg = logf(uu) - log1pf(-uu);
      float z = mui + acc[m] + lg;
      op[m] = (z > 0.0f) ? 1.0f : 0.0f;
    }
    float4* hp = (float4*)(hard + ((size_t)b * NSEG + i) * MC);
#pragma unroll
    for (int q = 0; q < 4; ++q) hp[q] = outv[q];
  }
}

// ---------------- K3: mask gather, one float4 per thread -------------------
__global__ __launch_bounds__(256) void mask_kernel(
    const int* __restrict__ groups, const float* __restrict__ hard,
    float4* __restrict__ out) {
  int f = blockIdx.x * blockDim.x + threadIdx.x;  // float4 index
  if (f >= BATCH * 3 * HW * 4) return;
  int pix = f >> 2;          // (b*3+c)*HW + p
  int q = f & 3;
  int b = pix / (3 * HW);
  int p = pix % HW;
  int g = groups[b * HW + p];
  out[f] = ((const float4*)hard)[(b * NSEG + g) * 4 + q];
}

extern "C" void kernel_launch(void* const* d_in, const int* in_sizes, int n_in,
                              void* d_out, int out_size, void* d_ws, size_t ws_size,
                              hipStream_t stream) {
  const float* x = (const float*)d_in[0];
  const int* groups = (const int*)d_in[1];
  const float* Wc = (const float*)d_in[2];
  const float* bc = (const float*)d_in[3];

  float* out = (float*)d_out;
  float* mask_out = out;                         // 38,535,168
  float* gp_out = out + 38535168;                //      3,136
  float* pp_out = gp_out + 3136;                 //    802,816
  float* sig_out = pp_out + 802816;              //    614,656

  float* ws = (float*)d_ws;
  float* partial = ws;                           // 224*784 = 175,616
  float* hard    = ws + 175616;                  //  50,176 (own region)

  emb_kernel<<<BATCH * EBLK, 256, 0, stream>>>(x, groups, Wc, bc, partial, pp_out);

  uint32_t kg0, kg1, ku0, ku1;
  threefry2x32(0u, 42u, 0u, 0u, kg0, kg1);
  threefry2x32(0u, 42u, 0u, 1u, ku0, ku1);

  fused_kernel<<<BATCH, 256, 0, stream>>>(partial, Wc, bc, kg0, kg1, ku0, ku1,
                                          gp_out, sig_out, hard);
  mask_kernel<<<(BATCH * 3 * HW * 4 + 255) / 256, 256, 0, stream>>>(
      groups, hard, (float4*)mask_out);
}

// Round 15
// 251.598 us; speedup vs baseline: 1.1429x; 1.1429x over previous
//
#include <hip/hip_runtime.h>
#include <stdint.h>

#define HW    50176   // 224*224
#define BATCH 16
#define NSEG  196
#define EMB   16
#define MC    16
#define JITTER 0.001f
#define EBLK  14      // emb blocks per batch
#define PXB   3584    // pixels per emb block (50176/14)

// ---------------- threefry2x32 (20 rounds), bit-exact vs JAX ----------------
__host__ __device__ inline void threefry2x32(uint32_t k0, uint32_t k1,
                                             uint32_t x0, uint32_t x1,
                                             uint32_t& o0, uint32_t& o1) {
  uint32_t k2 = k0 ^ k1 ^ 0x1BD11BDAu;
#define TFR(r) { x0 += x1; x1 = (x1 << (r)) | (x1 >> (32 - (r))); x1 ^= x0; }
  x0 += k0; x1 += k1;
  TFR(13) TFR(15) TFR(26) TFR(6)
  x0 += k1; x1 += k2 + 1u;
  TFR(17) TFR(29) TFR(16) TFR(24)
  x0 += k2; x1 += k0 + 2u;
  TFR(13) TFR(15) TFR(26) TFR(6)
  x0 += k0; x1 += k1 + 3u;
  TFR(17) TFR(29) TFR(16) TFR(24)
  x0 += k1; x1 += k2 + 4u;
  TFR(13) TFR(15) TFR(26) TFR(6)
  x0 += k2; x1 += k0 + 5u;
#undef TFR
  o0 = x0; o1 = x1;
}

// XLA ErfInv (f32), Giles polynomial
__device__ inline float erfinv_f32(float x) {
  float w = -log1pf(-x * x);
  float p;
  if (w < 5.0f) {
    w = w - 2.5f;
    p = 2.81022636e-08f;
    p = 3.43273939e-07f + p * w;
    p = -3.5233877e-06f + p * w;
    p = -4.39150654e-06f + p * w;
    p = 0.00021858087f + p * w;
    p = -0.00125372503f + p * w;
    p = -0.00417768164f + p * w;
    p = 0.246640727f + p * w;
    p = 1.50140941f + p * w;
  } else {
    w = sqrtf(w) - 3.0f;
    p = -0.000200214257f;
    p = 0.000100950558f + p * w;
    p = 0.00134934322f + p * w;
    p = -0.00367342844f + p * w;
    p = 0.00573950773f + p * w;
    p = -0.0076224613f + p * w;
    p = 0.00943887047f + p * w;
    p = 1.00167406f + p * w;
    p = 2.83297682f + p * w;
  }
  return p * x;
}

__device__ inline float bits_to_f01(uint32_t bits) {
  uint32_t fb = (bits >> 9) | 0x3F800000u;
  return __uint_as_float(fb) - 1.0f;
}

// serial j-ascending dot (bit-identity requires this exact order)
__device__ inline float dot15(const float a[15], const float b[15]) {
  float d = 0.0f;
#pragma unroll
  for (int j = 0; j < 15; ++j) d = fmaf(a[j], b[j], d);
  return d;
}

// R11 tree-norm + rsq/rcp scalar chain (verbatim; passing numerics)
__device__ inline void pivot_scalars(const float gk[15], float& invd,
                                     float& dd, float& beta) {
  const float sj = 0.031622776601683794f;  // sqrt(jitter)
  float t0 = fmaf(gk[0], gk[0], JITTER);
  float t1 = gk[1] * gk[1];   float t2 = gk[2] * gk[2];
  float t3 = gk[3] * gk[3];   float t4 = gk[4] * gk[4];
  float t5 = gk[5] * gk[5];   float t6 = gk[6] * gk[6];
  float t7 = gk[7] * gk[7];   float t8 = gk[8] * gk[8];
  float t9 = gk[9] * gk[9];   float t10 = gk[10] * gk[10];
  float t11 = gk[11] * gk[11]; float t12 = gk[12] * gk[12];
  float t13 = gk[13] * gk[13]; float t14 = gk[14] * gk[14];
  float u0 = t0 + t1, u1 = t2 + t3, u2 = t4 + t5, u3 = t6 + t7;
  float u4 = t8 + t9, u5 = t10 + t11, u6 = t12 + t13;
  float v0 = u0 + u1, v1 = u2 + u3, v2 = u4 + u5, v3 = u6 + t14;
  float jn = (v0 + v1) + (v2 + v3);
  invd = __builtin_amdgcn_rsqf(jn);
  dd = jn * invd;
  beta = (invd * invd) * __builtin_amdgcn_rcpf(fmaf(sj, invd, 1.0f));
}

// ---------------- K1: pixel_probs + per-block segment sums of x,cnt --------
__global__ __launch_bounds__(256) void emb_kernel(
    const float* __restrict__ x, const int* __restrict__ groups,
    const float* __restrict__ Wc, const float* __restrict__ bc,
    float* __restrict__ partial, float* __restrict__ pixel_probs) {
  __shared__ float lsum[4 * NSEG];  // [c][g]
  int b = blockIdx.x / EBLK;
  int blk = blockIdx.x % EBLK;
  int tid = threadIdx.x;
  for (int i = tid; i < 4 * NSEG; i += 256) lsum[i] = 0.0f;
  __syncthreads();
  const float* xb = x + (size_t)b * 3 * HW;
  float w0 = Wc[0], w1 = Wc[1], w2 = Wc[2], b0 = bc[0];
  for (int k = 0; k < PXB / 256; ++k) {
    int p = blk * PXB + k * 256 + tid;
    float x0 = xb[p], x1 = xb[HW + p], x2 = xb[2 * HW + p];
    int g = groups[b * HW + p];
    float e = w0 * x0 + w1 * x1;
    e = e + w2 * x2 + b0;
    pixel_probs[b * HW + p] = 1.0f / (1.0f + expf(-e));
    atomicAdd(&lsum[g], x0);
    atomicAdd(&lsum[NSEG + g], x1);
    atomicAdd(&lsum[2 * NSEG + g], x2);
    atomicAdd(&lsum[3 * NSEG + g], 1.0f);
  }
  __syncthreads();
  float* pb = partial + (size_t)blockIdx.x * (4 * NSEG);
  if (tid < NSEG) {
#pragma unroll
    for (int c = 0; c < 4; ++c) pb[c * NSEG + tid] = lsum[c * NSEG + tid];
  }
}

// ---------------- K2: main — sigma tile blocks + chol blocks ---------------
// Grid 128: blocks [0,112) compute sigma tiles (R12 structure, recompute ge
// from partials — cheap, same fma order -> bit-identical); blocks [112,128)
// run stats + eps + 4-pivot-interval Cholesky + hard.
// Chol: per barrier interval t (49 total; 196 = 4*49), the 4 owners of panel
// t published their raw rows (updated through pivot 4t-1) last interval.
// EVERY thread derives the 4 finished pivots locally with the serial
// algorithm's exact op order (p0=r0; r1-=beta0*(r1.p0)*p0 -> p1; r2: p0,p1;
// r3: p0,p1,p2; scalars via the R11 chain), then applies all 4 to its own
// row ascending (dot -> w -> acc -> update, same per-(i,k) sequence as
// R12/R13).  Barriers 196 -> 49; derivation replication is issue-only.
// Bit-identical output to rounds 11-14.
__global__ __launch_bounds__(256, 1) void main_kernel(
    const float* __restrict__ partial, const float* __restrict__ Wc,
    const float* __restrict__ bc,
    uint32_t kg0, uint32_t kg1, uint32_t ku0, uint32_t ku1,
    float* __restrict__ group_probs, float* __restrict__ sigma_out,
    float* __restrict__ hard) {
  int bid = blockIdx.x;
  int tid = threadIdx.x;

  if (bid < 112) {
    // ================= sigma tile block =================
    int b = bid / 7;
    int tile = bid % 7;
    __shared__ float ge_s[15][NSEG];
    if (tid < NSEG) {
      float sx0 = 0.0f, sx1 = 0.0f, sx2 = 0.0f, cn = 0.0f;
      for (int bb = 0; bb < EBLK; ++bb) {
        const float* pb = partial + (size_t)(b * EBLK + bb) * (4 * NSEG);
        sx0 += pb[tid]; sx1 += pb[NSEG + tid];
        sx2 += pb[2 * NSEG + tid]; cn += pb[3 * NSEG + tid];
      }
      float denom = fmaxf(cn, 1.0f);
#pragma unroll
      for (int j = 1; j < EMB; ++j) {
        float e = Wc[j * 3 + 0] * sx0 + Wc[j * 3 + 1] * sx1;
        e = e + Wc[j * 3 + 2] * sx2 + bc[j] * cn;
        ge_s[j - 1][tid] = e / denom;
      }
    }
    __syncthreads();
    if (tid < NSEG) {
      int t = tid;
      float gt[15];
#pragma unroll
      for (int j = 0; j < 15; ++j) gt[j] = ge_s[j][t];
      for (int r = 0; r < 28; ++r) {
        int s = tile * 28 + r;
        float a = 0.0f;
#pragma unroll
        for (int j = 0; j < 15; ++j) a = fmaf(ge_s[j][s], gt[j], a);
        if (s == t) a += JITTER;
        sigma_out[((size_t)b * NSEG + s) * NSEG + t] = a;
      }
    }
    return;
  }

  // ================= chol block =================
  int b = bid - 112;
  __shared__ float ge[15][NSEG];                 // 11.76 KB
  __shared__ float mu_l[NSEG];
  __shared__ float eps_lds[NSEG * MC];           // 12.25 KB
  __shared__ __align__(16) float pbuf[2][4][16]; // raw next-panel rows

  // eps = sqrt(2)*erfinv(bits) straight into LDS
  for (int t = tid; t < NSEG * MC; t += 256) {
    uint32_t a0, a1;
    threefry2x32(kg0, kg1, 0u, (uint32_t)(b * NSEG * MC + t), a0, a1);
    float f = bits_to_f01(a0 ^ a1);
    const float lo = -0.99999994f;  // nextafter(-1,0)
    float u = fmaxf(lo, f * (1.0f - lo) + lo);
    eps_lds[t] = 1.4142135623730951f * erfinv_f32(u);
  }

  // stats (identical op order to R12-R14)
  if (tid < NSEG) {
    float sx0 = 0.0f, sx1 = 0.0f, sx2 = 0.0f, cn = 0.0f;
    for (int bb = 0; bb < EBLK; ++bb) {
      const float* pb = partial + (size_t)(b * EBLK + bb) * (4 * NSEG);
      sx0 += pb[tid]; sx1 += pb[NSEG + tid];
      sx2 += pb[2 * NSEG + tid]; cn += pb[3 * NSEG + tid];
    }
    float denom = fmaxf(cn, 1.0f);
#pragma unroll
    for (int j = 0; j < EMB; ++j) {
      float e = Wc[j * 3 + 0] * sx0 + Wc[j * 3 + 1] * sx1;
      e = e + Wc[j * 3 + 2] * sx2 + bc[j] * cn;
      float v = e / denom;
      if (j == 0) {
        mu_l[tid] = v;
        group_probs[b * NSEG + tid] = 1.0f / (1.0f + expf(-v));
      } else {
        ge[j - 1][tid] = v;
      }
    }
  }
  __syncthreads();  // ge, mu_l, eps_lds visible

  int i = tid;  // this thread's row
  float g[15];
#pragma unroll
  for (int j = 0; j < 15; ++j) g[j] = (i < NSEG) ? ge[j][i] : 0.0f;
  float acc[16];
#pragma unroll
  for (int m = 0; m < 16; ++m) acc[m] = 0.0f;
  if (tid < 4) {  // publish raw rows 0..3 for interval 0
    float* pw = &pbuf[0][tid][0];
#pragma unroll
    for (int j = 0; j < 15; ++j) pw[j] = g[j];
  }
  __syncthreads();

// apply one finished pivot (row rv, index K) to own row — exact R13 sequence
#define APPLY_PIVOT(rv, invd_, dd_, beta_, K)                               \
  {                                                                         \
    float dot = dot15(g, rv);                                               \
    float w = (i > (K)) ? dot * (invd_)                                     \
                        : ((i == (K)) ? (dd_) : 0.0f);                      \
    const float4* ep = (const float4*)(eps_lds + (K) * MC);                 \
    float4 e0 = ep[0], e1 = ep[1], e2 = ep[2], e3 = ep[3];                  \
    float ek[16] = {e0.x, e0.y, e0.z, e0.w, e1.x, e1.y, e1.z, e1.w,         \
                    e2.x, e2.y, e2.z, e2.w, e3.x, e3.y, e3.z, e3.w};        \
    _Pragma("unroll")                                                       \
    for (int m = 0; m < 16; ++m) acc[m] = fmaf(w, ek[m], acc[m]);           \
    float bd = (beta_) * dot;                                               \
    _Pragma("unroll")                                                       \
    for (int j = 0; j < 15; ++j) g[j] = fmaf(-bd, rv[j], g[j]);             \
  }

  for (int t49 = 0; t49 < 49; ++t49) {
    const float* pb0 = &pbuf[t49 & 1][0][0];
    float r0[15], r1[15], r2[15], r3[15];
    {
      float4 a0 = *(const float4*)(pb0 + 0);
      float4 a1 = *(const float4*)(pb0 + 4);
      float4 a2 = *(const float4*)(pb0 + 8);
      float4 a3 = *(const float4*)(pb0 + 12);
      r0[0]=a0.x; r0[1]=a0.y; r0[2]=a0.z; r0[3]=a0.w;
      r0[4]=a1.x; r0[5]=a1.y; r0[6]=a1.z; r0[7]=a1.w;
      r0[8]=a2.x; r0[9]=a2.y; r0[10]=a2.z; r0[11]=a2.w;
      r0[12]=a3.x; r0[13]=a3.y; r0[14]=a3.z;
      a0 = *(const float4*)(pb0 + 16); a1 = *(const float4*)(pb0 + 20);
      a2 = *(const float4*)(pb0 + 24); a3 = *(const float4*)(pb0 + 28);
      r1[0]=a0.x; r1[1]=a0.y; r1[2]=a0.z; r1[3]=a0.w;
      r1[4]=a1.x; r1[5]=a1.y; r1[6]=a1.z; r1[7]=a1.w;
      r1[8]=a2.x; r1[9]=a2.y; r1[10]=a2.z; r1[11]=a2.w;
      r1[12]=a3.x; r1[13]=a3.y; r1[14]=a3.z;
      a0 = *(const float4*)(pb0 + 32); a1 = *(const float4*)(pb0 + 36);
      a2 = *(const float4*)(pb0 + 40); a3 = *(const float4*)(pb0 + 44);
      r2[0]=a0.x; r2[1]=a0.y; r2[2]=a0.z; r2[3]=a0.w;
      r2[4]=a1.x; r2[5]=a1.y; r2[6]=a1.z; r2[7]=a1.w;
      r2[8]=a2.x; r2[9]=a2.y; r2[10]=a2.z; r2[11]=a2.w;
      r2[12]=a3.x; r2[13]=a3.y; r2[14]=a3.z;
      a0 = *(const float4*)(pb0 + 48); a1 = *(const float4*)(pb0 + 52);
      a2 = *(const float4*)(pb0 + 56); a3 = *(const float4*)(pb0 + 60);
      r3[0]=a0.x; r3[1]=a0.y; r3[2]=a0.z; r3[3]=a0.w;
      r3[4]=a1.x; r3[5]=a1.y; r3[6]=a1.z; r3[7]=a1.w;
      r3[8]=a2.x; r3[9]=a2.y; r3[10]=a2.z; r3[11]=a2.w;
      r3[12]=a3.x; r3[13]=a3.y; r3[14]=a3.z;
    }
    // derive the 4 finished pivots (exact serial op order)
    float invd0, dd0, beta0, invd1, dd1, beta1;
    float invd2, dd2, beta2, invd3, dd3, beta3;
    pivot_scalars(r0, invd0, dd0, beta0);
    {
      float d = dot15(r1, r0); float bd = beta0 * d;
#pragma unroll
      for (int j = 0; j < 15; ++j) r1[j] = fmaf(-bd, r0[j], r1[j]);
    }
    pivot_scalars(r1, invd1, dd1, beta1);
    {
      float d = dot15(r2, r0); float bd = beta0 * d;
#pragma unroll
      for (int j = 0; j < 15; ++j) r2[j] = fmaf(-bd, r0[j], r2[j]);
      d = dot15(r2, r1); bd = beta1 * d;
#pragma unroll
      for (int j = 0; j < 15; ++j) r2[j] = fmaf(-bd, r1[j], r2[j]);
    }
    pivot_scalars(r2, invd2, dd2, beta2);
    {
      float d = dot15(r3, r0); float bd = beta0 * d;
#pragma unroll
      for (int j = 0; j < 15; ++j) r3[j] = fmaf(-bd, r0[j], r3[j]);
      d = dot15(r3, r1); bd = beta1 * d;
#pragma unroll
      for (int j = 0; j < 15; ++j) r3[j] = fmaf(-bd, r1[j], r3[j]);
      d = dot15(r3, r2); bd = beta2 * d;
#pragma unroll
      for (int j = 0; j < 15; ++j) r3[j] = fmaf(-bd, r2[j], r3[j]);
    }
    pivot_scalars(r3, invd3, dd3, beta3);

    // apply 4 pivots to own row, ascending k
    int k0 = 4 * t49;
    APPLY_PIVOT(r0, invd0, dd0, beta0, k0 + 0)
    APPLY_PIVOT(r1, invd1, dd1, beta1, k0 + 1)
    APPLY_PIVOT(r2, invd2, dd2, beta2, k0 + 2)
    APPLY_PIVOT(r3, invd3, dd3, beta3, k0 + 3)

    // publish raw rows for next interval (owners: rows 4(t+1)..4(t+1)+3)
    int nb = 4 * (t49 + 1);
    if (i >= nb && i < nb + 4) {  // t49=48 -> rows 196..199: zeros, never read
      float* pw = &pbuf[(t49 + 1) & 1][i - nb][0];
#pragma unroll
      for (int j = 0; j < 15; ++j) pw[j] = g[j];
    }
    __syncthreads();
  }
#undef APPLY_PIVOT

  // epilogue: hard = (mu + L@eps + logistic) > 0
  if (i < NSEG) {
    float mui = mu_l[i];
    float4 outv[4];
    float* op = (float*)outv;
#pragma unroll
    for (int m = 0; m < 16; ++m) {
      uint32_t a0, a1;
      threefry2x32(ku0, ku1, 0u, (uint32_t)(b * NSEG * MC + i * MC + m), a0, a1);
      float f = bits_to_f01(a0 ^ a1);
      const float mn = 1e-6f;
      const float mx = (float)(1.0 - 1e-6);
      float uu = fmaxf(mn, f * (mx - mn) + mn);
      float lg = logf(uu) - log1pf(-uu);
      float z = mui + acc[m] + lg;
      op[m] = (z > 0.0f) ? 1.0f : 0.0f;
    }
    float4* hp = (float4*)(hard + ((size_t)b * NSEG + i) * MC);
#pragma unroll
    for (int q = 0; q < 4; ++q) hp[q] = outv[q];
  }
}

// ---------------- K3: mask gather, one float4 per thread -------------------
__global__ __launch_bounds__(256) void mask_kernel(
    const int* __restrict__ groups, const float* __restrict__ hard,
    float4* __restrict__ out) {
  int f = blockIdx.x * blockDim.x + threadIdx.x;  // float4 index
  if (f >= BATCH * 3 * HW * 4) return;
  int pix = f >> 2;          // (b*3+c)*HW + p
  int q = f & 3;
  int b = pix / (3 * HW);
  int p = pix % HW;
  int g = groups[b * HW + p];
  out[f] = ((const float4*)hard)[(b * NSEG + g) * 4 + q];
}

extern "C" void kernel_launch(void* const* d_in, const int* in_sizes, int n_in,
                              void* d_out, int out_size, void* d_ws, size_t ws_size,
                              hipStream_t stream) {
  const float* x = (const float*)d_in[0];
  const int* groups = (const int*)d_in[1];
  const float* Wc = (const float*)d_in[2];
  const float* bc = (const float*)d_in[3];

  float* out = (float*)d_out;
  float* mask_out = out;                         // 38,535,168
  float* gp_out = out + 38535168;                //      3,136
  float* pp_out = gp_out + 3136;                 //    802,816
  float* sig_out = pp_out + 802816;              //    614,656

  float* ws = (float*)d_ws;
  float* partial = ws;                           // 224*784 = 175,616
  float* hard    = ws + 175616;                  //  50,176 (own region)

  emb_kernel<<<BATCH * EBLK, 256, 0, stream>>>(x, groups, Wc, bc, partial, pp_out);

  uint32_t kg0, kg1, ku0, ku1;
  threefry2x32(0u, 42u, 0u, 0u, kg0, kg1);
  threefry2x32(0u, 42u, 0u, 1u, ku0, ku1);

  main_kernel<<<128, 256, 0, stream>>>(partial, Wc, bc, kg0, kg1, ku0, ku1,
                                       gp_out, sig_out, hard);
  mask_kernel<<<(BATCH * 3 * HW * 4 + 255) / 256, 256, 0, stream>>>(
      groups, hard, (float4*)mask_out);
}